// Round 4
// baseline (620.987 us; speedup 1.0000x reference)
//
#include <hip/hip_runtime.h>
#include <math.h>

// ---------------- problem constants ----------------
// B=2, IMG=512, FMC=1024, HID=512, A=9, NC=21, RED=16, POOL=7, TOP=20
// fm spatial 32x32. GEMMs: conv1 2048x1024x768, rpn 2048x512x9216, fc 40x1024x50176.

#define NEGV (-1e30f)

typedef unsigned short u16;
typedef float v4f __attribute__((ext_vector_type(4)));
typedef short short8 __attribute__((ext_vector_type(8)));

// output offsets (floats)
#define O_RPN_REG 0
#define O_RPN_CLS 73728
#define O_NMS_REG 92160
#define O_NMS_CLS 92320
#define O_RCNN_REG 92360
#define O_RCNN_CLS 92520
#define O_ANCH 93360

// workspace offsets (floats)
#define W_FM   0u            // 2048*1024 fm NHWC fp32 (atomic conv1 accumulator, pre-biased)
#define W_ZERO 2097152u      // 64 zero floats (OOB redirect page for global_load_lds)
#define W_PROP 3145728u      // 2*9216*4
#define W_SCR  3219456u      // 2*9216
#define W_FLAT 3237888u      // 40*50176
#define W_HF   5244928u      // 40*1024
#define W_A1H  5285888u      // 2048*768 u16 -> 786432 floats
#define W_A1L  6072320u
#define W_B1H  6858752u      // 1024*768 u16 -> 393216 floats
#define W_B1L  7251968u
#define W_FMH  7645184u      // 2048*1024 u16 -> 1048576 floats
#define W_FML  8693760u
#define W_B2H  9742336u      // 512*9216 u16 -> 2359296 floats
#define W_B2L  12101632u
#define W_PART 14460928u     // 2048*512 fp32: rpn atomic accumulator (pre-biased)
// end = 16,558,080 floats = 66.2 MB

static __device__ __forceinline__ float relu_(float v) { return fmaxf(v, 0.0f); }

// async global -> LDS, 16B per lane. LDS dest is wave-uniform-base + lane*16;
// our per-lane pointers satisfy base + L*16 exactly, so passing them is consistent.
static __device__ __forceinline__ void gload16(const void* g, void* l) {
    __builtin_amdgcn_global_load_lds(
        (const __attribute__((address_space(1))) unsigned int*)g,
        (__attribute__((address_space(3))) unsigned int*)l, 16, 0, 0);
}

// fp32 -> bf16 hi/lo split (RTNE)
static __device__ __forceinline__ u16 bf16_rtne(float x) {
    unsigned int u = __float_as_uint(x);
    unsigned int r = u + 0x7fffu + ((u >> 16) & 1u);
    return (u16)(r >> 16);
}
static __device__ __forceinline__ void split2(float x, u16& h, u16& l) {
    h = bf16_rtne(x);
    const float hf = __uint_as_float(((unsigned int)h) << 16);
    l = bf16_rtne(x - hf);
}
// split 8 fp32 (register array) -> 16B hi + 16B lo LDS stores
static __device__ __forceinline__ void split8_store(const float* v, u16* dsth, u16* dstl) {
    uint4 H, Lo;
    u16 h0, l0, h1, l1;
    split2(v[0], h0, l0); split2(v[1], h1, l1);
    H.x = (unsigned)h0 | ((unsigned)h1 << 16); Lo.x = (unsigned)l0 | ((unsigned)l1 << 16);
    split2(v[2], h0, l0); split2(v[3], h1, l1);
    H.y = (unsigned)h0 | ((unsigned)h1 << 16); Lo.y = (unsigned)l0 | ((unsigned)l1 << 16);
    split2(v[4], h0, l0); split2(v[5], h1, l1);
    H.z = (unsigned)h0 | ((unsigned)h1 << 16); Lo.z = (unsigned)l0 | ((unsigned)l1 << 16);
    split2(v[6], h0, l0); split2(v[7], h1, l1);
    H.w = (unsigned)h0 | ((unsigned)h1 << 16); Lo.w = (unsigned)l0 | ((unsigned)l1 << 16);
    *(uint4*)dsth = H; *(uint4*)dstl = Lo;
}

// anchor half-extents, bit-matching numpy f64 -> f32
static __device__ __forceinline__ void anchor_wh(int a, float& w2, float& h2) {
    double s = (a < 3) ? 64.0 : (a < 6) ? 128.0 : 256.0;
    int rm = a - (a / 3) * 3;
    double r = (rm == 0) ? 0.5 : (rm == 1) ? 1.0 : 2.0;
    double sq = sqrt(r);
    w2 = (float)(s * sq) * 0.5f;
    h2 = (float)(s / sq) * 0.5f;
}

// ---------------- fused prep: im2col + cnn_w split + rpn w transpose + fm bias init ----------------
// blocks [0,1536): a1 im2col; [1536,2304): cnn_w split4; [2304,2816): w2 transpose;
// [2816,4864): fm[m][c] = cnn_b[c] (atomic-accumulator bias pre-init)
__global__ __launch_bounds__(256) void k_prep_all(
        const float* __restrict__ img, u16* __restrict__ a1h, u16* __restrict__ a1l,
        float* __restrict__ zbuf,
        const float* __restrict__ cnnw, u16* __restrict__ b1h, u16* __restrict__ b1l,
        const float* __restrict__ rpnw, u16* __restrict__ b2h, u16* __restrict__ b2l,
        const float* __restrict__ cnnb, float* __restrict__ fm) {
    __shared__ __align__(16) u16 sh[9216];
    __shared__ __align__(16) u16 sl[9216];
    const int bx = blockIdx.x, tid = threadIdx.x;
    if (bx < 1536) {
        if (bx == 0 && tid < 64) zbuf[tid] = 0.0f;
        const int idx = bx * 256 + tid;        // 393216
        const int m = idx / 192, kq = (idx - m * 192) * 4;
        const int b = m >> 10, i = (m >> 5) & 31, j = m & 31;
        const int c = kq >> 8, rem = kq & 255, y = rem >> 4, x = rem & 15;
        const float4 v = *(const float4*)(img + ((size_t)((b * 3 + c) * 512 + i * 16 + y)) * 512 + j * 16 + x);
        ushort4 H, Lo;
        split2(v.x, H.x, Lo.x); split2(v.y, H.y, Lo.y);
        split2(v.z, H.z, Lo.z); split2(v.w, H.w, Lo.w);
        *(ushort4*)(a1h + (size_t)idx * 4) = H;
        *(ushort4*)(a1l + (size_t)idx * 4) = Lo;
    } else if (bx < 2304) {
        const int idx = (bx - 1536) * 256 + tid;   // 196608 exactly
        const float4 v = *(const float4*)(cnnw + (size_t)idx * 4);
        ushort4 H, Lo;
        split2(v.x, H.x, Lo.x); split2(v.y, H.y, Lo.y);
        split2(v.z, H.z, Lo.z); split2(v.w, H.w, Lo.w);
        *(ushort4*)(b1h + (size_t)idx * 4) = H;
        *(ushort4*)(b1l + (size_t)idx * 4) = Lo;
    } else if (bx < 2816) {
        const int oc = bx - 2304;                  // 512 blocks
        const float* p = rpnw + (size_t)oc * 9216;
        for (int i = tid * 4; i < 9216; i += 1024) {
            const float4 v = *(const float4*)(p + i);
            ushort4 H, Lo;
            split2(v.x, H.x, Lo.x); split2(v.y, H.y, Lo.y);
            split2(v.z, H.z, Lo.z); split2(v.w, H.w, Lo.w);
            *(ushort4*)(sh + i) = H;
            *(ushort4*)(sl + i) = Lo;
        }
        __syncthreads();
        const int ic4 = tid * 4;
#pragma unroll
        for (int d = 0; d < 9; ++d) {
            ushort4 H, Lo;
            H.x = sh[(ic4 + 0) * 9 + d]; Lo.x = sl[(ic4 + 0) * 9 + d];
            H.y = sh[(ic4 + 1) * 9 + d]; Lo.y = sl[(ic4 + 1) * 9 + d];
            H.z = sh[(ic4 + 2) * 9 + d]; Lo.z = sl[(ic4 + 2) * 9 + d];
            H.w = sh[(ic4 + 3) * 9 + d]; Lo.w = sl[(ic4 + 3) * 9 + d];
            const size_t o = (size_t)oc * 9216 + d * 1024 + ic4;
            *(ushort4*)(b2h + o) = H;
            *(ushort4*)(b2l + o) = Lo;
        }
    } else {
        const size_t o = ((size_t)(bx - 2816) * 256 + tid) * 4;   // 2M floats
        *(float4*)(fm + o) = *(const float4*)(cnnb + (o & 1023));
    }
}

// ---------------- MFMA bf16x3 GEMM, 128x128 tile, atomic split-K epilogue ----------------
// 256 thr = 4 waves, wave tile 64x64, K-chunk 32, 48 MFMA/wave/chunk vs 16 ds_read_b128.
// LDS 64 KB (double-buffered 4x[128][32] u16) -> 2 blocks/CU.
// Staging: global_load_lds dwordx4, one barrier per chunk (implicit vmcnt(0) handoff).
// Epilogue: atomicAdd into a pre-biased fp32 accumulator (any split-K order).
// MODE 0 (conv1): A linear rows. MODE 1 (rpn): gather A from fm bf16 h/l, OOB -> zbuf.
template<int MODE>
__global__ __launch_bounds__(256, 2) void k_gemm(
        const u16* __restrict__ Agh, const u16* __restrict__ Agl,
        const u16* __restrict__ Bgh, const u16* __restrict__ Bgl,
        float* __restrict__ Cacc,
        const int KA, const int KB, const int nchunk, const int ldc,
        const float* __restrict__ zbuf) {
    __shared__ __align__(16) u16 AsH[2 * 128 * 32];
    __shared__ __align__(16) u16 AsL[2 * 128 * 32];
    __shared__ __align__(16) u16 BsH[2 * 128 * 32];
    __shared__ __align__(16) u16 BsL[2 * 128 * 32];
    const int tid = threadIdx.x;
    const int w = tid >> 6, L = tid & 63;
    const int q = L >> 4, lr = L & 15;
    const int wm = w >> 1, wn = w & 1;
    const int m0 = blockIdx.x * 128, n0 = blockIdx.y * 128;
    const int zbase = blockIdx.z * nchunk;
    const int rr = tid >> 2, seg = tid & 3;

    // staging: s=0..7 -> buffer s>>1 (0=AH 1=AL 2=BH 3=BL), half=s&1, row = half*64+rr
    u16* lbase[8];
    const u16* gb[8];
    long aoff[2]; int ai[2], aj[2];
#pragma unroll
    for (int s = 0; s < 8; ++s) {
        const int buf = s >> 1, half = s & 1;
        const int r = half * 64 + rr;
        u16* lb = (buf == 0) ? AsH : (buf == 1) ? AsL : (buf == 2) ? BsH : BsL;
        lbase[s] = lb + (half * 256 + tid) * 8;
        if (buf >= 2) {
            const u16* g0 = (buf == 2) ? Bgh : Bgl;
            gb[s] = g0 + (size_t)(n0 + r) * KB + seg * 8;
        } else if (MODE == 0) {
            const u16* g0 = (buf == 0) ? Agh : Agl;
            gb[s] = g0 + (size_t)(m0 + r) * KA + seg * 8;
        } else {
            const int m = m0 + r;
            const int b_ = m >> 10, i_ = (m >> 5) & 31, j_ = m & 31;
            if (buf == 0) { aoff[half] = (long)b_ * 1048576 + seg * 8; ai[half] = i_; aj[half] = j_; }
            gb[s] = (buf == 0) ? Agh : Agl;
        }
    }

    v4f acc[4][4];
#pragma unroll
    for (int t = 0; t < 4; ++t)
#pragma unroll
        for (int u = 0; u < 4; ++u) acc[t][u] = (v4f){0.f, 0.f, 0.f, 0.f};

#define ISSUE(c_, bb_) do { \
    const int g_ = zbase + (c_); \
    int d_ = 0, ic_ = 0; \
    if (MODE == 1) { d_ = g_ >> 5; ic_ = (g_ & 31) << 5; } \
    const int kOff_ = (MODE == 0) ? g_ * 32 : (d_ * 1024 + ic_); \
    const int di_ = d_ / 3, dj_ = d_ - di_ * 3; \
    long goffA_[2]; bool okA_[2]; \
    if (MODE == 1) { \
        _Pragma("unroll") \
        for (int h_ = 0; h_ < 2; ++h_) { \
            const int y_ = ai[h_] + di_ - 1, x_ = aj[h_] + dj_ - 1; \
            okA_[h_] = ((unsigned)y_ < 32u) && ((unsigned)x_ < 32u); \
            goffA_[h_] = aoff[h_] + (long)(okA_[h_] ? y_ : 0) * 32768 \
                       + (long)(okA_[h_] ? x_ : 0) * 1024 + ic_; \
        } \
    } \
    _Pragma("unroll") \
    for (int s = 0; s < 8; ++s) { \
        const u16* gsrc_; \
        if (MODE == 0 || s >= 4) gsrc_ = gb[s] + kOff_; \
        else gsrc_ = okA_[s & 1] ? (gb[s] + goffA_[s & 1]) : (const u16*)zbuf; \
        gload16(gsrc_, lbase[s] + (bb_) * 4096); \
    } \
} while (0)

    int cur = 0;
    ISSUE(0, 0);
    for (int c = 0; c < nchunk; ++c) {
        __syncthreads();                        // drains vmcnt -> buf[cur] resident; WAR fence
        if (c + 1 < nchunk) ISSUE(c + 1, cur ^ 1);
        const int ao = cur * 4096;
        short8 ah[4], al[4], bh[4], bl[4];
#pragma unroll
        for (int t = 0; t < 4; ++t) {
            ah[t] = *(const short8*)(AsH + ao + (wm * 64 + t * 16 + lr) * 32 + q * 8);
            al[t] = *(const short8*)(AsL + ao + (wm * 64 + t * 16 + lr) * 32 + q * 8);
        }
#pragma unroll
        for (int u = 0; u < 4; ++u) {
            bh[u] = *(const short8*)(BsH + ao + (wn * 64 + u * 16 + lr) * 32 + q * 8);
            bl[u] = *(const short8*)(BsL + ao + (wn * 64 + u * 16 + lr) * 32 + q * 8);
        }
#pragma unroll
        for (int t = 0; t < 4; ++t)
#pragma unroll
            for (int u = 0; u < 4; ++u) {
                acc[t][u] = __builtin_amdgcn_mfma_f32_16x16x32_bf16(ah[t], bh[u], acc[t][u], 0, 0, 0);
                acc[t][u] = __builtin_amdgcn_mfma_f32_16x16x32_bf16(ah[t], bl[u], acc[t][u], 0, 0, 0);
                acc[t][u] = __builtin_amdgcn_mfma_f32_16x16x32_bf16(al[t], bh[u], acc[t][u], 0, 0, 0);
            }
        cur ^= 1;
    }
#undef ISSUE

#pragma unroll
    for (int t = 0; t < 4; ++t) {
        const int row = m0 + wm * 64 + t * 16 + q * 4;
#pragma unroll
        for (int u = 0; u < 4; ++u) {
            const int col = n0 + wn * 64 + u * 16 + lr;
#pragma unroll
            for (int r = 0; r < 4; ++r)
                atomicAdd(Cacc + (size_t)(row + r) * ldc + col, acc[t][u][r]);
        }
    }
}

// ---------------- conv1 finish: fm = relu(fm) in place, emit bf16 h/l split ----------------
// Also pre-inits the rpn atomic accumulator partB[m][c] = rpn_b[c] (first 262144 threads).
__global__ void k_c1_reduce(const float* __restrict__ rpnb, float* __restrict__ partB,
                            float* __restrict__ fm, u16* __restrict__ fmh, u16* __restrict__ fml) {
    const int gid = blockIdx.x * 256 + threadIdx.x;        // 524288
    const size_t o = (size_t)gid * 4;
    float4 a = *(const float4*)(fm + o);
    a.x = relu_(a.x); a.y = relu_(a.y); a.z = relu_(a.z); a.w = relu_(a.w);
    *(float4*)(fm + o) = a;
    ushort4 H, Lo;
    split2(a.x, H.x, Lo.x); split2(a.y, H.y, Lo.y);
    split2(a.z, H.z, Lo.z); split2(a.w, H.w, Lo.w);
    *(ushort4*)(fmh + o) = H;
    *(ushort4*)(fml + o) = Lo;
    if (gid < 262144) {
        const int c = (gid * 4) & 511;
        *(float4*)(partB + (size_t)gid * 4) = *(const float4*)(rpnb + c);
    }
}

// ---------------- rpn heads v3: 256 blocks x 4 waves, 8 rows/block, single accumulator ----------------
__global__ __launch_bounds__(256) void k_rpn_heads2(const float* __restrict__ partB,
        const float* __restrict__ regw, const float* __restrict__ regb,
        const float* __restrict__ clsw, const float* __restrict__ clsb,
        float* __restrict__ out, float* __restrict__ prop, float* __restrict__ scr) {
    __shared__ __align__(16) float hrow[8][512];
    const int tid = threadIdx.x;
    const int m0 = blockIdx.x * 8;             // 256 blocks
#pragma unroll
    for (int i = 0; i < 4; ++i) {
        const int f = i * 256 + tid;           // 0..1023 float4 tasks
        const int r = f >> 7, c4 = (f & 127) * 4;
        const float4 p = *(const float4*)(partB + (size_t)(m0 + r) * 512 + c4);
        float4 o;
        o.x = relu_(p.x); o.y = relu_(p.y); o.z = relu_(p.z); o.w = relu_(p.w);
        *(float4*)&hrow[r][c4] = o;
    }
    __syncthreads();
    const int w = tid >> 6, lane = tid & 63;
#pragma unroll
    for (int rr = 0; rr < 2; ++rr) {
        const int lrow = w * 2 + rr;
        const int m = m0 + lrow;
        const int b = m >> 10, qd = m & 1023, ii = qd >> 5, jj = qd & 31;
        const float cx = ((float)jj + 0.5f) * 16.f, cy = ((float)ii + 0.5f) * 16.f;
        if (lane < 45) {
            const int isreg = (lane < 36);
            const float* wp = isreg ? (regw + (size_t)lane * 512) : (clsw + (size_t)(lane - 36) * 512);
            float acc2 = isreg ? regb[lane] : clsb[lane - 36];
            const float* hr = hrow[lrow];
            for (int k = 0; k < 512; k += 4) {
                const float4 wv = *(const float4*)(wp + k);
                acc2 += hr[k + 0] * wv.x; acc2 += hr[k + 1] * wv.y;
                acc2 += hr[k + 2] * wv.z; acc2 += hr[k + 3] * wv.w;
            }
            if (isreg) {
                out[O_RPN_REG + (size_t)b * 36864 + qd * 36 + lane] = acc2;
                const int a = lane >> 2, cc = lane & 3;
                float w2, h2; anchor_wh(a, w2, h2);
                const float av = (cc == 0) ? cx - w2 : (cc == 1) ? cy - h2 : (cc == 2) ? cx + w2 : cy + h2;
                prop[(size_t)b * 36864 + qd * 36 + lane] = acc2 + av;
            } else {
                const int n = lane - 36;
                out[O_RPN_CLS + (size_t)b * 9216 + qd * 9 + n] = acc2;
                scr[(size_t)b * 9216 + qd * 9 + n] = acc2;
            }
        } else if (b == 0 && lane < 54) {
            const int a = lane - 45;
            float w2, h2; anchor_wh(a, w2, h2);
            const float4 av4 = make_float4(cx - w2, cy - h2, cx + w2, cy + h2);
            *(float4*)(out + O_ANCH + (size_t)(qd * 9 + a) * 4) = av4;
        }
    }
}

// ---------------- NMS v3: 512 thr, 18 cand/thread, ALL static register indexing ----------------
__global__ __launch_bounds__(512) void k_nms3(const float* __restrict__ prop,
        const float* __restrict__ scr, float* __restrict__ out) {
    __shared__ float wv_[2][8];
    __shared__ int wi_[2][8];
    const int b = blockIdx.x, tid = threadIdx.x;
    const int lane = tid & 63, wid = tid >> 6;
    const float* P = prop + (size_t)b * 36864;
    float4 bx[18]; float sv[18];
#pragma unroll
    for (int k = 0; k < 18; ++k) {
        const int i = tid * 18 + k;
        bx[k] = *(const float4*)(P + (size_t)i * 4);
        sv[k] = scr[b * 9216 + i];
    }
    for (int t = 0; t < 20; ++t) {
        float bv = -3.4e38f; int bi = 0;
#pragma unroll
        for (int k = 0; k < 18; ++k)
            if (sv[k] > bv) { bv = sv[k]; bi = tid * 18 + k; }   // ascending idx -> first max kept
#pragma unroll
        for (int off = 1; off < 64; off <<= 1) {
            const float ov = __shfl_xor(bv, off);
            const int oi = __shfl_xor(bi, off);
            if (ov > bv || (ov == bv && oi < bi)) { bv = ov; bi = oi; }
        }
        if (lane == 0) { wv_[t & 1][wid] = bv; wi_[t & 1][wid] = bi; }
        __syncthreads();
        float rb = wv_[t & 1][0]; int sel = wi_[t & 1][0];
#pragma unroll
        for (int j = 1; j < 8; ++j) {
            const float v2 = wv_[t & 1][j]; const int i2 = wi_[t & 1][j];
            if (v2 > rb || (v2 == rb && i2 < sel)) { rb = v2; sel = i2; }
        }
        const float4 bb = *(const float4*)(P + (size_t)sel * 4);   // broadcast read
        if (tid == 0) {
            *(float4*)(out + O_NMS_REG + (size_t)(b * 20 + t) * 4) = bb;
            out[O_NMS_CLS + b * 20 + t] = rb;
        }
        const float ab2 = fmaxf(bb.z - bb.x, 0.f) * fmaxf(bb.w - bb.y, 0.f);
#pragma unroll
        for (int k = 0; k < 18; ++k) {
            const float ix1 = fmaxf(bb.x, bx[k].x), iy1 = fmaxf(bb.y, bx[k].y);
            const float ix2 = fminf(bb.z, bx[k].z), iy2 = fminf(bb.w, bx[k].w);
            const float inter = fmaxf(ix2 - ix1, 0.f) * fmaxf(iy2 - iy1, 0.f);
            const float ar2 = fmaxf(bx[k].z - bx[k].x, 0.f) * fmaxf(bx[k].w - bx[k].y, 0.f);
            const float iou = inter / (ab2 + ar2 - inter + 1e-8f);
            if (iou > 0.3f || (tid * 18 + k) == sel) sv[k] = NEGV;
        }
    }
}

// ---------------- ROI align -> flat [40][50176] + fused hf bias-init ----------------
__global__ __launch_bounds__(256) void k_roi(const float* __restrict__ fm,
        const int* __restrict__ img_id, const float* __restrict__ nreg,
        float* __restrict__ flat, const float* __restrict__ fcb, float* __restrict__ hf) {
    __shared__ float tile[12544];              // 256 * 49 floats = 50 KB
    const int hid = (((blockIdx.z * 20 + blockIdx.y) * 4) + blockIdx.x) * 256 + threadIdx.x;
    hf[hid] = fcb[hid & 1023];
    const int c0 = blockIdx.x * 256;
    const int roi = blockIdx.y, b = blockIdx.z;
    const float* bx = nreg + (size_t)(b * 20 + roi) * 4;
    const float b0 = bx[0] * 0.0625f, b1 = bx[1] * 0.0625f;
    const float b2 = bx[2] * 0.0625f, b3 = bx[3] * 0.0625f;
    const float wd = fmaxf(b2 - b0, 0.f), hg = fmaxf(b3 - b1, 0.f);
    const int bb = img_id[b];
    const float* fmb = fm + (size_t)bb * (32 * 32 * 1024);
    const int c = c0 + threadIdx.x;
    for (int py = 0; py < 7; ++py) {
        const float tyv = ((float)py + 0.5f) / 7.0f;
        const float ycv = fminf(fmaxf(b1 + hg * tyv, 0.f), 31.f);
        const float y0f = floorf(ycv);
        const int y0 = (int)y0f, y1 = min(y0 + 1, 31);
        const float ly = ycv - y0f, omly = 1.f - ly;
        for (int px = 0; px < 7; ++px) {
            const float txv = ((float)px + 0.5f) / 7.0f;
            const float xcv = fminf(fmaxf(b0 + wd * txv, 0.f), 31.f);
            const float x0f = floorf(xcv);
            const int x0 = (int)x0f, x1 = min(x0 + 1, 31);
            const float lx = xcv - x0f, omlx = 1.f - lx;
            const int o00 = ((y0 * 32) + x0) << 10, o01 = ((y0 * 32) + x1) << 10;
            const int o10 = ((y1 * 32) + x0) << 10, o11 = ((y1 * 32) + x1) << 10;
            const float v00 = fmb[o00 + c], v01 = fmb[o01 + c];
            const float v10 = fmb[o10 + c], v11 = fmb[o11 + c];
            tile[threadIdx.x * 49 + py * 7 + px] =
                ((v00 * omly) * omlx) + ((v01 * omly) * lx)
                + ((v10 * ly) * omlx) + ((v11 * ly) * lx);
        }
    }
    __syncthreads();
    const size_t ob = (size_t)(b * 20 + roi) * 50176 + (size_t)c0 * 49;
    for (int i = threadIdx.x * 4; i < 12544; i += 1024)
        *(float4*)(flat + ob + i) = *(const float4*)&tile[i];
}

// ---------------- FC GEMM MFMA bf16x3: 40(pad48) x 1024 x 50176, n-tile 128 ----------------
__global__ __launch_bounds__(256, 2) void k_fc_mfma(const float* __restrict__ flat,
        const float* __restrict__ fcw, float* __restrict__ hf) {
    __shared__ __align__(16) u16 AsH[4 * 48 * 8];
    __shared__ __align__(16) u16 AsL[4 * 48 * 8];
    __shared__ __align__(16) u16 BsH[4 * 128 * 8];
    __shared__ __align__(16) u16 BsL[4 * 128 * 8];
    const int tid = threadIdx.x;
    const int w = tid >> 6, L = tid & 63, q = L >> 4, lr = L & 15;
    const int n0 = blockIdx.x * 128, kb = blockIdx.y * 512;
    if (tid < 32) {
        const int oct = tid >> 3, m = 40 + (tid & 7);
        *(uint4*)(AsH + (oct * 48 + m) * 8) = make_uint4(0, 0, 0, 0);
        *(uint4*)(AsL + (oct * 48 + m) * 8) = make_uint4(0, 0, 0, 0);
    }
    const int am = tid >> 2, aoct = tid & 3;
    const float* abase = flat + (size_t)am * 50176 + kb + aoct * 8;
    const int bcolI = tid & 127, bkh = tid >> 7;       // col 0..127, k-half 0..1
    const float* bcol = fcw + n0 + bcolI;

    v4f acc[3][2];
#pragma unroll
    for (int mt = 0; mt < 3; ++mt)
#pragma unroll
        for (int nt = 0; nt < 2; ++nt) acc[mt][nt] = (v4f){0.f, 0.f, 0.f, 0.f};

    float areg[8];
    float breg[2][8];

#define LOADF(c_) do { \
    if (tid < 160) { \
        const float4 u_ = *(const float4*)(abase + (c_) * 32); \
        const float4 v_ = *(const float4*)(abase + (c_) * 32 + 4); \
        areg[0] = u_.x; areg[1] = u_.y; areg[2] = u_.z; areg[3] = u_.w; \
        areg[4] = v_.x; areg[5] = v_.y; areg[6] = v_.z; areg[7] = v_.w; \
    } \
    _Pragma("unroll") \
    for (int o_ = 0; o_ < 2; ++o_) \
        _Pragma("unroll") \
        for (int j_ = 0; j_ < 8; ++j_) \
            breg[o_][j_] = bcol[(size_t)(kb + (c_) * 32 + bkh * 16 + o_ * 8 + j_) * 1024]; \
} while (0)

    LOADF(0);
    for (int c = 0; c < 16; ++c) {
        __syncthreads();
        if (tid < 160)
            split8_store(areg, AsH + (aoct * 48 + am) * 8, AsL + (aoct * 48 + am) * 8);
#pragma unroll
        for (int o = 0; o < 2; ++o)
            split8_store(breg[o], BsH + ((bkh * 2 + o) * 128 + bcolI) * 8,
                                  BsL + ((bkh * 2 + o) * 128 + bcolI) * 8);
        __syncthreads();
        if (c + 1 < 16) LOADF(c + 1);
        short8 ah[3], al[3], bh2[2], bl2[2];
#pragma unroll
        for (int mt = 0; mt < 3; ++mt) {
            ah[mt] = *(const short8*)(AsH + (q * 48 + mt * 16 + lr) * 8);
            al[mt] = *(const short8*)(AsL + (q * 48 + mt * 16 + lr) * 8);
        }
#pragma unroll
        for (int nt = 0; nt < 2; ++nt) {
            bh2[nt] = *(const short8*)(BsH + (q * 128 + w * 32 + nt * 16 + lr) * 8);
            bl2[nt] = *(const short8*)(BsL + (q * 128 + w * 32 + nt * 16 + lr) * 8);
        }
#pragma unroll
        for (int mt = 0; mt < 3; ++mt)
#pragma unroll
            for (int nt = 0; nt < 2; ++nt) {
                acc[mt][nt] = __builtin_amdgcn_mfma_f32_16x16x32_bf16(ah[mt], bh2[nt], acc[mt][nt], 0, 0, 0);
                acc[mt][nt] = __builtin_amdgcn_mfma_f32_16x16x32_bf16(ah[mt], bl2[nt], acc[mt][nt], 0, 0, 0);
                acc[mt][nt] = __builtin_amdgcn_mfma_f32_16x16x32_bf16(al[mt], bh2[nt], acc[mt][nt], 0, 0, 0);
            }
    }
#undef LOADF

#pragma unroll
    for (int mt = 0; mt < 3; ++mt) {
#pragma unroll
        for (int nt = 0; nt < 2; ++nt) {
#pragma unroll
            for (int r = 0; r < 4; ++r) {
                const int row = mt * 16 + q * 4 + r;
                if (row < 40)
                    atomicAdd(hf + (size_t)row * 1024 + n0 + w * 32 + nt * 16 + lr, acc[mt][nt][r]);
            }
        }
    }
}

// ---------------- final heads ----------------
__global__ __launch_bounds__(64) void k_heads(const float* __restrict__ hf,
        const float* __restrict__ regw, const float* __restrict__ regb,
        const float* __restrict__ clsw, const float* __restrict__ clsb,
        float* __restrict__ out) {
    __shared__ __align__(16) float hrow[1024];
    const int m = blockIdx.x, tid = threadIdx.x;
    for (int i = tid * 4; i < 1024; i += 256) {
        const float4 v = *(const float4*)(hf + (size_t)m * 1024 + i);
        hrow[i + 0] = relu_(v.x); hrow[i + 1] = relu_(v.y);
        hrow[i + 2] = relu_(v.z); hrow[i + 3] = relu_(v.w);
    }
    __syncthreads();
    if (tid < 25) {
        float acc2 = 0.f;
        if (tid < 4) {
            for (int k = 0; k < 1024; ++k) acc2 += hrow[k] * regw[(size_t)k * 4 + tid];
            out[O_RCNN_REG + m * 4 + tid] = acc2 + regb[tid];
        } else {
            const int n = tid - 4;
            for (int k = 0; k < 1024; ++k) acc2 += hrow[k] * clsw[(size_t)k * 21 + n];
            out[O_RCNN_CLS + m * 21 + n] = acc2 + clsb[n];
        }
    }
}

extern "C" void kernel_launch(void* const* d_in, const int* in_sizes, int n_in,
                              void* d_out, int out_size, void* d_ws, size_t ws_size,
                              hipStream_t stream) {
    (void)in_sizes; (void)n_in; (void)out_size; (void)ws_size;
    const float* img       = (const float*)d_in[0];
    const int*   img_id    = (const int*)  d_in[1];
    const float* cnn_w     = (const float*)d_in[2];
    const float* cnn_b     = (const float*)d_in[3];
    const float* rpn_w     = (const float*)d_in[4];
    const float* rpn_b     = (const float*)d_in[5];
    const float* rpn_reg_w = (const float*)d_in[6];
    const float* rpn_reg_b = (const float*)d_in[7];
    const float* rpn_cls_w = (const float*)d_in[8];
    const float* rpn_cls_b = (const float*)d_in[9];
    const float* fc_w      = (const float*)d_in[10];
    const float* fc_b      = (const float*)d_in[11];
    const float* reg_w     = (const float*)d_in[12];
    const float* reg_b     = (const float*)d_in[13];
    const float* cls_w     = (const float*)d_in[14];
    const float* cls_b     = (const float*)d_in[15];
    float* out = (float*)d_out;
    float* ws  = (float*)d_ws;

    float* fm   = ws + W_FM;
    float* zbuf = ws + W_ZERO;
    float* prop = ws + W_PROP;
    float* scr  = ws + W_SCR;
    float* flat = ws + W_FLAT;
    float* hf   = ws + W_HF;
    u16* a1h = (u16*)(ws + W_A1H);
    u16* a1l = (u16*)(ws + W_A1L);
    u16* b1h = (u16*)(ws + W_B1H);
    u16* b1l = (u16*)(ws + W_B1L);
    u16* fmh = (u16*)(ws + W_FMH);
    u16* fml = (u16*)(ws + W_FML);
    u16* b2h = (u16*)(ws + W_B2H);
    u16* b2l = (u16*)(ws + W_B2L);
    float* partB = ws + W_PART;   // rpn atomic accumulator 2048x512 fp32 (pre-biased)

    // fused prep: im2col + cnn_w split + rpn w transpose + zbuf init + fm bias init
    k_prep_all<<<4864, 256, 0, stream>>>(img, a1h, a1l, zbuf, cnn_w, b1h, b1l,
                                         rpn_w, b2h, b2l, cnn_b, fm);
    // conv1: 128x128 tile, split-K 4, atomicAdd into pre-biased fm
    k_gemm<0><<<dim3(16, 8, 4), 256, 0, stream>>>(a1h, a1l, b1h, b1l, fm,
                                                  768, 768, 6, 1024, zbuf);
    // finish conv1 (relu + bf16 split) + pre-bias rpn accumulator
    k_c1_reduce<<<2048, 256, 0, stream>>>(rpn_b, partB, fm, fmh, fml);
    // rpn: 128x128 tile, split-K 8 over 288 chunks, atomicAdd into pre-biased partB
    k_gemm<1><<<dim3(16, 4, 8), 256, 0, stream>>>(fmh, fml, b2h, b2l, partB,
                                                  1024, 9216, 36, 512, zbuf);
    k_rpn_heads2<<<256, 256, 0, stream>>>(partB, rpn_reg_w, rpn_reg_b, rpn_cls_w, rpn_cls_b,
                                          out, prop, scr);
    k_nms3<<<2, 512, 0, stream>>>(prop, scr, out);
    k_roi<<<dim3(4, 20, 2), 256, 0, stream>>>(fm, img_id, out + O_NMS_REG, flat, fc_b, hf);
    k_fc_mfma<<<dim3(8, 98), 256, 0, stream>>>(flat, fc_w, hf);
    k_heads<<<40, 64, 0, stream>>>(hf, reg_w, reg_b, cls_w, cls_b, out);
}

// Round 5
// 581.797 us; speedup vs baseline: 1.0674x; 1.0674x over previous
//
#include <hip/hip_runtime.h>
#include <math.h>

// ---------------- problem constants ----------------
// B=2, IMG=512, FMC=1024, HID=512, A=9, NC=21, RED=16, POOL=7, TOP=20
// fm spatial 32x32. GEMMs: conv1 2048x1024x768, rpn 2048x512x9216, fc 40x1024x50176.

#define NEGV (-1e30f)

typedef unsigned short u16;
typedef float v4f __attribute__((ext_vector_type(4)));
typedef short short8 __attribute__((ext_vector_type(8)));

// output offsets (floats)
#define O_RPN_REG 0
#define O_RPN_CLS 73728
#define O_NMS_REG 92160
#define O_NMS_CLS 92320
#define O_RCNN_REG 92360
#define O_RCNN_CLS 92520
#define O_ANCH 93360

// workspace offsets (floats)
#define W_FM   0u            // 2048*1024 fm NHWC fp32 (conv1 split-K partial z=0)
#define W_ZERO 2097152u      // 64 zero floats (OOB redirect page for global_load_lds)
#define W_PROP 3145728u      // 2*9216*4
#define W_SCR  3219456u      // 2*9216
#define W_FLAT 3237888u      // 40*50176 (ALSO rpn split-K parts 0..3, dead region then)
#define W_HF   5244928u      // 40*1024
#define W_A1I  5285888u      // a1 interleaved: 2048*24*64 u16 = 1,572,864 floats
#define W_B1I  6858752u      // b1 interleaved: 1024*24*64 u16 = 786,432 floats
#define W_FMI  7645184u      // fm interleaved: 2048*32*64 u16 = 2,097,152 floats
#define W_B2I  9742336u      // b2 interleaved: 512*288*64 u16 = 4,718,592 floats
#define W_PART 14460928u     // 2048*1024 fp32: conv1 partial z=1, later rpn parts 4..5
// end = 16,558,080 floats = 66.2 MB

static __device__ __forceinline__ float relu_(float v) { return fmaxf(v, 0.0f); }

// async global -> LDS, 16B per lane. LDS dest is wave-uniform-base + lane*16.
static __device__ __forceinline__ void gload16(const void* g, void* l) {
    __builtin_amdgcn_global_load_lds(
        (const __attribute__((address_space(1))) unsigned int*)g,
        (__attribute__((address_space(3))) unsigned int*)l, 16, 0, 0);
}

// fp32 -> bf16 hi/lo split (RTNE)
static __device__ __forceinline__ u16 bf16_rtne(float x) {
    unsigned int u = __float_as_uint(x);
    unsigned int r = u + 0x7fffu + ((u >> 16) & 1u);
    return (u16)(r >> 16);
}
static __device__ __forceinline__ void split2(float x, u16& h, u16& l) {
    h = bf16_rtne(x);
    const float hf = __uint_as_float(((unsigned int)h) << 16);
    l = bf16_rtne(x - hf);
}
// split 8 fp32 -> 16B hi + 16B lo LDS stores
static __device__ __forceinline__ void split8_store(const float* v, u16* dsth, u16* dstl) {
    uint4 H, Lo;
    u16 h0, l0, h1, l1;
    split2(v[0], h0, l0); split2(v[1], h1, l1);
    H.x = (unsigned)h0 | ((unsigned)h1 << 16); Lo.x = (unsigned)l0 | ((unsigned)l1 << 16);
    split2(v[2], h0, l0); split2(v[3], h1, l1);
    H.y = (unsigned)h0 | ((unsigned)h1 << 16); Lo.y = (unsigned)l0 | ((unsigned)l1 << 16);
    split2(v[4], h0, l0); split2(v[5], h1, l1);
    H.z = (unsigned)h0 | ((unsigned)h1 << 16); Lo.z = (unsigned)l0 | ((unsigned)l1 << 16);
    split2(v[6], h0, l0); split2(v[7], h1, l1);
    H.w = (unsigned)h0 | ((unsigned)h1 << 16); Lo.w = (unsigned)l0 | ((unsigned)l1 << 16);
    *(uint4*)dsth = H; *(uint4*)dstl = Lo;
}

// anchor half-extents, bit-matching numpy f64 -> f32
static __device__ __forceinline__ void anchor_wh(int a, float& w2, float& h2) {
    double s = (a < 3) ? 64.0 : (a < 6) ? 128.0 : 256.0;
    int rm = a - (a / 3) * 3;
    double r = (rm == 0) ? 0.5 : (rm == 1) ? 1.0 : 2.0;
    double sq = sqrt(r);
    w2 = (float)(s * sq) * 0.5f;
    h2 = (float)(s / sq) * 0.5f;
}

// ============ interleaved bf16x2 layout: row-chunk = [2(hi/lo)][32] u16 = 128B ============
// element k of row m, chunk c: hi at base(m,c)+ (k&31), lo at +32, base = ((m*NCH + c)*64)

// ---------------- prep: conv1 im2col A (interleaved) + zero page init ----------------
__global__ void k_prep_a1(const float* __restrict__ img, u16* __restrict__ a1i,
                          float* __restrict__ zbuf) {
    if (blockIdx.x == 0 && threadIdx.x < 64) zbuf[threadIdx.x] = 0.0f;
    const int idx = blockIdx.x * 256 + threadIdx.x;        // 393216
    const int m = idx / 192, k = (idx - m * 192) * 4;      // k in [0,768), mult of 4
    const int b = m >> 10, i = (m >> 5) & 31, j = m & 31;
    const int c = k >> 8, rem = k & 255, y = rem >> 4, x = rem & 15;
    const float4 v = *(const float4*)(img + ((size_t)((b * 3 + c) * 512 + i * 16 + y)) * 512 + j * 16 + x);
    ushort4 H, Lo;
    split2(v.x, H.x, Lo.x); split2(v.y, H.y, Lo.y);
    split2(v.z, H.z, Lo.z); split2(v.w, H.w, Lo.w);
    const size_t base = ((size_t)m * 24 + (k >> 5)) * 64 + (k & 31);
    *(ushort4*)(a1i + base) = H;
    *(ushort4*)(a1i + base + 32) = Lo;
}

// ---------------- prep: cnn_w [1024][768] -> interleaved ----------------
__global__ void k_prep_b1(const float* __restrict__ src, u16* __restrict__ b1i) {
    const int idx = blockIdx.x * 256 + threadIdx.x;        // 196608
    const int p = idx * 4;
    const int n = p / 768, k = p - n * 768;
    const float4 v = *(const float4*)(src + (size_t)p);
    ushort4 H, Lo;
    split2(v.x, H.x, Lo.x); split2(v.y, H.y, Lo.y);
    split2(v.z, H.z, Lo.z); split2(v.w, H.w, Lo.w);
    const size_t base = ((size_t)n * 24 + (k >> 5)) * 64 + (k & 31);
    *(ushort4*)(b1i + base) = H;
    *(ushort4*)(b1i + base + 32) = Lo;
}

// ---------------- prep: rpn weights (512,1024,3,3) -> interleaved [oc][d*32+icc][2][32] ----------------
__global__ __launch_bounds__(256) void k_prep_w2(const float* __restrict__ w,
        u16* __restrict__ b2i) {
    __shared__ __align__(16) u16 sh[9216];
    __shared__ __align__(16) u16 sl[9216];
    const int oc = blockIdx.x;                 // 512 blocks
    const float* p = w + (size_t)oc * 9216;
    for (int i = threadIdx.x * 4; i < 9216; i += 1024) {
        const float4 v = *(const float4*)(p + i);
        ushort4 H, Lo;
        split2(v.x, H.x, Lo.x); split2(v.y, H.y, Lo.y);
        split2(v.z, H.z, Lo.z); split2(v.w, H.w, Lo.w);
        *(ushort4*)(sh + i) = H;
        *(ushort4*)(sl + i) = Lo;
    }
    __syncthreads();
    const int ic4 = threadIdx.x * 4;
#pragma unroll
    for (int d = 0; d < 9; ++d) {
        ushort4 H, Lo;
        H.x = sh[(ic4 + 0) * 9 + d]; Lo.x = sl[(ic4 + 0) * 9 + d];
        H.y = sh[(ic4 + 1) * 9 + d]; Lo.y = sl[(ic4 + 1) * 9 + d];
        H.z = sh[(ic4 + 2) * 9 + d]; Lo.z = sl[(ic4 + 2) * 9 + d];
        H.w = sh[(ic4 + 3) * 9 + d]; Lo.w = sl[(ic4 + 3) * 9 + d];
        const size_t base = ((size_t)oc * 288 + d * 32 + (ic4 >> 5)) * 64 + (ic4 & 31);
        *(ushort4*)(b2i + base) = H;
        *(ushort4*)(b2i + base + 32) = Lo;
    }
}

// ---------------- MFMA bf16x3 GEMM (conv1 / rpn), interleaved staging ----------------
// Block tile 128(M) x 64(N), 256 thr = 4 waves, wave tile 64x32, K-chunk 32.
// LDS: Ls[2 dbuf][192 rows][64 u16] = 48 KB -> 3 blocks/CU. Rows 0-127 = A, 128-191 = B.
// Staging: 6 x gload16/thread/chunk; each staged row-chunk is ONE 128B line (h[32]l[32]),
// global source seg pre-swizzled by XOR(row&7) so the linear LDS image is bank-spread;
// ds_read applies the same XOR -> floor-optimal b128 reads. One barrier per chunk.
// MODE 0: A/B linear; split-K via z (z0->Cout, z1->Cout2 raw partials).
// MODE 1: A gathered from fmi (3x3 halo), OOB lanes -> zbuf; z<4->Cout slices, else Cout2.
template<int MODE>
__global__ __launch_bounds__(256, 3) void k_gemm(
        const u16* __restrict__ Agi, const u16* __restrict__ Bgi,
        float* __restrict__ Cout, float* __restrict__ Cout2,
        const int AstrU, const int BstrU, const int nchunk, const int ldc,
        const float* __restrict__ zbuf) {
    __shared__ __align__(16) u16 Ls[2 * 192 * 64];
    const int tid = threadIdx.x;
    const int w = tid >> 6, L = tid & 63;
    const int q = L >> 4, lr = L & 15;
    const int wm = w >> 1, wn = w & 1;
    const int m0 = blockIdx.x * 128, n0 = blockIdx.y * 64;
    const int zbase = blockIdx.z * nchunk;
    float* C;
    if (MODE == 1) {
        C = (blockIdx.z < 4) ? (Cout + (size_t)blockIdx.z * (2048u * 512u))
                             : (Cout2 + (size_t)(blockIdx.z - 4) * (2048u * 512u));
    } else {
        C = (blockIdx.z == 0) ? Cout : Cout2;
    }
    const int rr8 = tid >> 3;
    const int segp = (tid & 7) ^ (rr8 & 7);     // pre-swizzled global segment

    // per-slot staging bases (slot s: rows s*32+rr8; s<4 = A, s>=4 = B)
    const u16* gbase[6];
    int mi[4], mj[4];
#pragma unroll
    for (int s = 0; s < 6; ++s) {
        if (s >= 4) {
            const int br = n0 + (s - 4) * 32 + rr8;
            gbase[s] = Bgi + (size_t)br * BstrU + segp * 8;
        } else if (MODE == 0) {
            gbase[s] = Agi + (size_t)(m0 + s * 32 + rr8) * AstrU + segp * 8;
        } else {
            const int m = m0 + s * 32 + rr8;
            const int b_ = m >> 10;
            mi[s] = (m >> 5) & 31; mj[s] = m & 31;
            gbase[s] = Agi + (size_t)b_ * 2097152 + segp * 8;   // 32*32*32*64
        }
    }
    // xor-swizzled ds_read slot offsets (u16)
    const int x7 = lr & 7;
    const int shh = (q ^ x7) << 3;
    const int shl = ((4 + q) ^ x7) << 3;

    v4f acc[4][2];
#pragma unroll
    for (int t = 0; t < 4; ++t)
#pragma unroll
        for (int u2 = 0; u2 < 2; ++u2) acc[t][u2] = (v4f){0.f, 0.f, 0.f, 0.f};

#define ISSUE(c_, bb_) do { \
    const int g_ = zbase + (c_); \
    int d_ = 0, icc_ = 0; \
    if (MODE == 1) { d_ = g_ >> 5; icc_ = g_ & 31; } \
    const int di_ = d_ / 3, dj_ = d_ - di_ * 3; \
    _Pragma("unroll") \
    for (int s = 0; s < 6; ++s) { \
        const u16* gsrc_; \
        if (s >= 4 || MODE == 0) gsrc_ = gbase[s] + (size_t)g_ * 64; \
        else { \
            const int y_ = mi[s] + di_ - 1, x_ = mj[s] + dj_ - 1; \
            const bool ok_ = ((unsigned)y_ < 32u) && ((unsigned)x_ < 32u); \
            gsrc_ = ok_ ? (gbase[s] + (size_t)(((y_ * 32) + x_) * 32 + icc_) * 64) \
                        : ((const u16*)zbuf + segp * 8); \
        } \
        gload16(gsrc_, Ls + (bb_) * 12288 + s * 2048 + tid * 8); \
    } \
} while (0)

    int cur = 0;
    ISSUE(0, 0);
    for (int c = 0; c < nchunk; ++c) {
        __syncthreads();                        // drains vmcnt -> buf[cur] resident; WAR fence
        if (c + 1 < nchunk) ISSUE(c + 1, cur ^ 1);
        const int ao = cur * 12288;
        short8 ah[4], al[4], bh[2], bl[2];
#pragma unroll
        for (int t = 0; t < 4; ++t) {
            const int rowA = wm * 64 + t * 16 + lr;
            ah[t] = *(const short8*)(Ls + ao + rowA * 64 + shh);
            al[t] = *(const short8*)(Ls + ao + rowA * 64 + shl);
        }
#pragma unroll
        for (int u2 = 0; u2 < 2; ++u2) {
            const int rowB = 128 + wn * 32 + u2 * 16 + lr;
            bh[u2] = *(const short8*)(Ls + ao + rowB * 64 + shh);
            bl[u2] = *(const short8*)(Ls + ao + rowB * 64 + shl);
        }
#pragma unroll
        for (int t = 0; t < 4; ++t)
#pragma unroll
            for (int u2 = 0; u2 < 2; ++u2) {
                acc[t][u2] = __builtin_amdgcn_mfma_f32_16x16x32_bf16(ah[t], bh[u2], acc[t][u2], 0, 0, 0);
                acc[t][u2] = __builtin_amdgcn_mfma_f32_16x16x32_bf16(ah[t], bl[u2], acc[t][u2], 0, 0, 0);
                acc[t][u2] = __builtin_amdgcn_mfma_f32_16x16x32_bf16(al[t], bh[u2], acc[t][u2], 0, 0, 0);
            }
        cur ^= 1;
    }
#undef ISSUE

#pragma unroll
    for (int t = 0; t < 4; ++t) {
        const int row = m0 + wm * 64 + t * 16 + q * 4;
#pragma unroll
        for (int u2 = 0; u2 < 2; ++u2) {
            const int col = n0 + wn * 32 + u2 * 16 + lr;
#pragma unroll
            for (int r = 0; r < 4; ++r)
                C[(size_t)(row + r) * ldc + col] = acc[t][u2][r];
        }
    }
}

// ---------------- conv1 reduce: fm = relu(p0+p1+bias), emit interleaved bf16 split ----------------
__global__ void k_c1_reduce(const float* __restrict__ p1, const float* __restrict__ cb,
                            float* __restrict__ fm, u16* __restrict__ fmi) {
    const int gid = blockIdx.x * 256 + threadIdx.x;        // 524288
    const size_t o = (size_t)gid * 4;
    float4 a = *(const float4*)(fm + o);
    const float4 b4 = *(const float4*)(p1 + o);
    const float4 bb = *(const float4*)(cb + (o & 1023));
    a.x = relu_(a.x + b4.x + bb.x);
    a.y = relu_(a.y + b4.y + bb.y);
    a.z = relu_(a.z + b4.z + bb.z);
    a.w = relu_(a.w + b4.w + bb.w);
    *(float4*)(fm + o) = a;
    ushort4 H, Lo;
    split2(a.x, H.x, Lo.x); split2(a.y, H.y, Lo.y);
    split2(a.z, H.z, Lo.z); split2(a.w, H.w, Lo.w);
    const int m = (int)(o >> 10), ic = (int)(o & 1023);
    const size_t base = ((size_t)m * 32 + (ic >> 5)) * 64 + (ic & 31);
    *(ushort4*)(fmi + base) = H;
    *(ushort4*)(fmi + base + 32) = Lo;
}

// ---------------- rpn heads: 256 blocks x 4 waves, 8 rows/block, 6-partial sum ----------------
__global__ __launch_bounds__(256) void k_rpn_heads2(const float* __restrict__ partA,
        const float* __restrict__ partB,
        const float* __restrict__ rpnb,
        const float* __restrict__ regw, const float* __restrict__ regb,
        const float* __restrict__ clsw, const float* __restrict__ clsb,
        float* __restrict__ out, float* __restrict__ prop, float* __restrict__ scr) {
    __shared__ __align__(16) float hrow[8][512];
    const int tid = threadIdx.x;
    const int m0 = blockIdx.x * 8;             // 256 blocks
#pragma unroll
    for (int i = 0; i < 4; ++i) {
        const int f = i * 256 + tid;           // 0..1023 float4 tasks
        const int r = f >> 7, c4 = (f & 127) * 4;
        const size_t ro = (size_t)(m0 + r) * 512 + c4;
        const float4 a0 = *(const float4*)(partA + ro);
        const float4 a1 = *(const float4*)(partA + 1048576u + ro);
        const float4 a2 = *(const float4*)(partA + 2097152u + ro);
        const float4 a3 = *(const float4*)(partA + 3145728u + ro);
        const float4 a4 = *(const float4*)(partB + ro);
        const float4 a5 = *(const float4*)(partB + 1048576u + ro);
        const float4 bb = *(const float4*)(rpnb + c4);
        float4 o;
        o.x = relu_(a0.x + a1.x + a2.x + a3.x + a4.x + a5.x + bb.x);
        o.y = relu_(a0.y + a1.y + a2.y + a3.y + a4.y + a5.y + bb.y);
        o.z = relu_(a0.z + a1.z + a2.z + a3.z + a4.z + a5.z + bb.z);
        o.w = relu_(a0.w + a1.w + a2.w + a3.w + a4.w + a5.w + bb.w);
        *(float4*)&hrow[r][c4] = o;
    }
    __syncthreads();
    const int w = tid >> 6, lane = tid & 63;
#pragma unroll
    for (int rr = 0; rr < 2; ++rr) {
        const int lrow = w * 2 + rr;
        const int m = m0 + lrow;
        const int b = m >> 10, qd = m & 1023, ii = qd >> 5, jj = qd & 31;
        const float cx = ((float)jj + 0.5f) * 16.f, cy = ((float)ii + 0.5f) * 16.f;
        if (lane < 45) {
            const int isreg = (lane < 36);
            const float* wp = isreg ? (regw + (size_t)lane * 512) : (clsw + (size_t)(lane - 36) * 512);
            float acc2 = isreg ? regb[lane] : clsb[lane - 36];
            const float* hr = hrow[lrow];
            for (int k = 0; k < 512; k += 4) {
                const float4 wv = *(const float4*)(wp + k);
                acc2 += hr[k + 0] * wv.x; acc2 += hr[k + 1] * wv.y;
                acc2 += hr[k + 2] * wv.z; acc2 += hr[k + 3] * wv.w;
            }
            if (isreg) {
                out[O_RPN_REG + (size_t)b * 36864 + qd * 36 + lane] = acc2;
                const int a = lane >> 2, cc = lane & 3;
                float w2, h2; anchor_wh(a, w2, h2);
                const float av = (cc == 0) ? cx - w2 : (cc == 1) ? cy - h2 : (cc == 2) ? cx + w2 : cy + h2;
                prop[(size_t)b * 36864 + qd * 36 + lane] = acc2 + av;
            } else {
                const int n = lane - 36;
                out[O_RPN_CLS + (size_t)b * 9216 + qd * 9 + n] = acc2;
                scr[(size_t)b * 9216 + qd * 9 + n] = acc2;
            }
        } else if (b == 0 && lane < 54) {
            const int a = lane - 45;
            float w2, h2; anchor_wh(a, w2, h2);
            const float4 av4 = make_float4(cx - w2, cy - h2, cx + w2, cy + h2);
            *(float4*)(out + O_ANCH + (size_t)(qd * 9 + a) * 4) = av4;
        }
    }
}

// ---------------- NMS v3: 512 thr, 18 cand/thread, ALL static register indexing ----------------
__global__ __launch_bounds__(512) void k_nms3(const float* __restrict__ prop,
        const float* __restrict__ scr, float* __restrict__ out) {
    __shared__ float wv_[2][8];
    __shared__ int wi_[2][8];
    const int b = blockIdx.x, tid = threadIdx.x;
    const int lane = tid & 63, wid = tid >> 6;
    const float* P = prop + (size_t)b * 36864;
    float4 bx[18]; float sv[18];
#pragma unroll
    for (int k = 0; k < 18; ++k) {
        const int i = tid * 18 + k;
        bx[k] = *(const float4*)(P + (size_t)i * 4);
        sv[k] = scr[b * 9216 + i];
    }
    for (int t = 0; t < 20; ++t) {
        float bv = -3.4e38f; int bi = 0;
#pragma unroll
        for (int k = 0; k < 18; ++k)
            if (sv[k] > bv) { bv = sv[k]; bi = tid * 18 + k; }   // ascending idx -> first max kept
#pragma unroll
        for (int off = 1; off < 64; off <<= 1) {
            const float ov = __shfl_xor(bv, off);
            const int oi = __shfl_xor(bi, off);
            if (ov > bv || (ov == bv && oi < bi)) { bv = ov; bi = oi; }
        }
        if (lane == 0) { wv_[t & 1][wid] = bv; wi_[t & 1][wid] = bi; }
        __syncthreads();
        float rb = wv_[t & 1][0]; int sel = wi_[t & 1][0];
#pragma unroll
        for (int j = 1; j < 8; ++j) {
            const float v2 = wv_[t & 1][j]; const int i2 = wi_[t & 1][j];
            if (v2 > rb || (v2 == rb && i2 < sel)) { rb = v2; sel = i2; }
        }
        const float4 bb = *(const float4*)(P + (size_t)sel * 4);   // broadcast read
        if (tid == 0) {
            *(float4*)(out + O_NMS_REG + (size_t)(b * 20 + t) * 4) = bb;
            out[O_NMS_CLS + b * 20 + t] = rb;
        }
        const float ab2 = fmaxf(bb.z - bb.x, 0.f) * fmaxf(bb.w - bb.y, 0.f);
#pragma unroll
        for (int k = 0; k < 18; ++k) {
            const float ix1 = fmaxf(bb.x, bx[k].x), iy1 = fmaxf(bb.y, bx[k].y);
            const float ix2 = fminf(bb.z, bx[k].z), iy2 = fminf(bb.w, bx[k].w);
            const float inter = fmaxf(ix2 - ix1, 0.f) * fmaxf(iy2 - iy1, 0.f);
            const float ar2 = fmaxf(bx[k].z - bx[k].x, 0.f) * fmaxf(bx[k].w - bx[k].y, 0.f);
            const float iou = inter / (ab2 + ar2 - inter + 1e-8f);
            if (iou > 0.3f || (tid * 18 + k) == sel) sv[k] = NEGV;
        }
    }
}

// ---------------- ROI align -> flat [40][50176] + fused hf bias-init ----------------
__global__ __launch_bounds__(256) void k_roi(const float* __restrict__ fm,
        const int* __restrict__ img_id, const float* __restrict__ nreg,
        float* __restrict__ flat, const float* __restrict__ fcb, float* __restrict__ hf) {
    __shared__ float tile[12544];              // 256 * 49 floats = 50 KB
    const int hid = (((blockIdx.z * 20 + blockIdx.y) * 4) + blockIdx.x) * 256 + threadIdx.x;
    hf[hid] = fcb[hid & 1023];
    const int c0 = blockIdx.x * 256;
    const int roi = blockIdx.y, b = blockIdx.z;
    const float* bx = nreg + (size_t)(b * 20 + roi) * 4;
    const float b0 = bx[0] * 0.0625f, b1 = bx[1] * 0.0625f;
    const float b2 = bx[2] * 0.0625f, b3 = bx[3] * 0.0625f;
    const float wd = fmaxf(b2 - b0, 0.f), hg = fmaxf(b3 - b1, 0.f);
    const int bb = img_id[b];
    const float* fmb = fm + (size_t)bb * (32 * 32 * 1024);
    const int c = c0 + threadIdx.x;
    for (int py = 0; py < 7; ++py) {
        const float tyv = ((float)py + 0.5f) / 7.0f;
        const float ycv = fminf(fmaxf(b1 + hg * tyv, 0.f), 31.f);
        const float y0f = floorf(ycv);
        const int y0 = (int)y0f, y1 = min(y0 + 1, 31);
        const float ly = ycv - y0f, omly = 1.f - ly;
        for (int px = 0; px < 7; ++px) {
            const float txv = ((float)px + 0.5f) / 7.0f;
            const float xcv = fminf(fmaxf(b0 + wd * txv, 0.f), 31.f);
            const float x0f = floorf(xcv);
            const int x0 = (int)x0f, x1 = min(x0 + 1, 31);
            const float lx = xcv - x0f, omlx = 1.f - lx;
            const int o00 = ((y0 * 32) + x0) << 10, o01 = ((y0 * 32) + x1) << 10;
            const int o10 = ((y1 * 32) + x0) << 10, o11 = ((y1 * 32) + x1) << 10;
            const float v00 = fmb[o00 + c], v01 = fmb[o01 + c];
            const float v10 = fmb[o10 + c], v11 = fmb[o11 + c];
            tile[threadIdx.x * 49 + py * 7 + px] =
                ((v00 * omly) * omlx) + ((v01 * omly) * lx)
                + ((v10 * ly) * omlx) + ((v11 * ly) * lx);
        }
    }
    __syncthreads();
    const size_t ob = (size_t)(b * 20 + roi) * 50176 + (size_t)c0 * 49;
    for (int i = threadIdx.x * 4; i < 12544; i += 1024)
        *(float4*)(flat + ob + i) = *(const float4*)&tile[i];
}

// ---------------- FC GEMM MFMA bf16x3: 40(pad48) x 1024 x 50176 (R2 version) ----------------
__global__ __launch_bounds__(256, 2) void k_fc_mfma(const float* __restrict__ flat,
        const float* __restrict__ fcw, float* __restrict__ hf) {
    __shared__ __align__(16) u16 AsH[4 * 48 * 8];
    __shared__ __align__(16) u16 AsL[4 * 48 * 8];
    __shared__ __align__(16) u16 BsH[4 * 256 * 8];
    __shared__ __align__(16) u16 BsL[4 * 256 * 8];
    const int tid = threadIdx.x;
    const int w = tid >> 6, L = tid & 63, q = L >> 4, lr = L & 15;
    const int n0 = blockIdx.x * 256, kb = blockIdx.y * 512;
    if (tid < 32) {
        const int oct = tid >> 3, m = 40 + (tid & 7);
        *(uint4*)(AsH + (oct * 48 + m) * 8) = make_uint4(0, 0, 0, 0);
        *(uint4*)(AsL + (oct * 48 + m) * 8) = make_uint4(0, 0, 0, 0);
    }
    const int am = tid >> 2, aoct = tid & 3;
    const float* abase = flat + (size_t)am * 50176 + kb + aoct * 8;
    const float* bcol = fcw + n0 + tid;

    v4f acc[3][4];
#pragma unroll
    for (int mt = 0; mt < 3; ++mt)
#pragma unroll
        for (int nt = 0; nt < 4; ++nt) acc[mt][nt] = (v4f){0.f, 0.f, 0.f, 0.f};

    float areg[8];
    float breg[4][8];

#define LOADF(c_) do { \
    if (tid < 160) { \
        const float4 u_ = *(const float4*)(abase + (c_) * 32); \
        const float4 v_ = *(const float4*)(abase + (c_) * 32 + 4); \
        areg[0] = u_.x; areg[1] = u_.y; areg[2] = u_.z; areg[3] = u_.w; \
        areg[4] = v_.x; areg[5] = v_.y; areg[6] = v_.z; areg[7] = v_.w; \
    } \
    _Pragma("unroll") \
    for (int o_ = 0; o_ < 4; ++o_) \
        _Pragma("unroll") \
        for (int j_ = 0; j_ < 8; ++j_) \
            breg[o_][j_] = bcol[(size_t)(kb + (c_) * 32 + o_ * 8 + j_) * 1024]; \
} while (0)

    LOADF(0);
    for (int c = 0; c < 16; ++c) {
        __syncthreads();
        if (tid < 160)
            split8_store(areg, AsH + (aoct * 48 + am) * 8, AsL + (aoct * 48 + am) * 8);
#pragma unroll
        for (int o = 0; o < 4; ++o)
            split8_store(breg[o], BsH + (o * 256 + tid) * 8, BsL + (o * 256 + tid) * 8);
        __syncthreads();
        if (c + 1 < 16) LOADF(c + 1);
        short8 ah[3], al[3], bh2[4], bl2[4];
#pragma unroll
        for (int mt = 0; mt < 3; ++mt) {
            ah[mt] = *(const short8*)(AsH + (q * 48 + mt * 16 + lr) * 8);
            al[mt] = *(const short8*)(AsL + (q * 48 + mt * 16 + lr) * 8);
        }
#pragma unroll
        for (int nt = 0; nt < 4; ++nt) {
            bh2[nt] = *(const short8*)(BsH + (q * 256 + w * 64 + nt * 16 + lr) * 8);
            bl2[nt] = *(const short8*)(BsL + (q * 256 + w * 64 + nt * 16 + lr) * 8);
        }
#pragma unroll
        for (int mt = 0; mt < 3; ++mt)
#pragma unroll
            for (int nt = 0; nt < 4; ++nt) {
                acc[mt][nt] = __builtin_amdgcn_mfma_f32_16x16x32_bf16(ah[mt], bh2[nt], acc[mt][nt], 0, 0, 0);
                acc[mt][nt] = __builtin_amdgcn_mfma_f32_16x16x32_bf16(ah[mt], bl2[nt], acc[mt][nt], 0, 0, 0);
                acc[mt][nt] = __builtin_amdgcn_mfma_f32_16x16x32_bf16(al[mt], bh2[nt], acc[mt][nt], 0, 0, 0);
            }
    }
#undef LOADF

#pragma unroll
    for (int mt = 0; mt < 3; ++mt) {
#pragma unroll
        for (int nt = 0; nt < 4; ++nt) {
#pragma unroll
            for (int r = 0; r < 4; ++r) {
                const int row = mt * 16 + q * 4 + r;
                if (row < 40)
                    atomicAdd(hf + (size_t)row * 1024 + n0 + w * 64 + nt * 16 + lr, acc[mt][nt][r]);
            }
        }
    }
}

// ---------------- final heads ----------------
__global__ __launch_bounds__(64) void k_heads(const float* __restrict__ hf,
        const float* __restrict__ regw, const float* __restrict__ regb,
        const float* __restrict__ clsw, const float* __restrict__ clsb,
        float* __restrict__ out) {
    __shared__ __align__(16) float hrow[1024];
    const int m = blockIdx.x, tid = threadIdx.x;
    for (int i = tid * 4; i < 1024; i += 256) {
        const float4 v = *(const float4*)(hf + (size_t)m * 1024 + i);
        hrow[i + 0] = relu_(v.x); hrow[i + 1] = relu_(v.y);
        hrow[i + 2] = relu_(v.z); hrow[i + 3] = relu_(v.w);
    }
    __syncthreads();
    if (tid < 25) {
        float acc2 = 0.f;
        if (tid < 4) {
            for (int k = 0; k < 1024; ++k) acc2 += hrow[k] * regw[(size_t)k * 4 + tid];
            out[O_RCNN_REG + m * 4 + tid] = acc2 + regb[tid];
        } else {
            const int n = tid - 4;
            for (int k = 0; k < 1024; ++k) acc2 += hrow[k] * clsw[(size_t)k * 21 + n];
            out[O_RCNN_CLS + m * 21 + n] = acc2 + clsb[n];
        }
    }
}

extern "C" void kernel_launch(void* const* d_in, const int* in_sizes, int n_in,
                              void* d_out, int out_size, void* d_ws, size_t ws_size,
                              hipStream_t stream) {
    (void)in_sizes; (void)n_in; (void)out_size; (void)ws_size;
    const float* img       = (const float*)d_in[0];
    const int*   img_id    = (const int*)  d_in[1];
    const float* cnn_w     = (const float*)d_in[2];
    const float* cnn_b     = (const float*)d_in[3];
    const float* rpn_w     = (const float*)d_in[4];
    const float* rpn_b     = (const float*)d_in[5];
    const float* rpn_reg_w = (const float*)d_in[6];
    const float* rpn_reg_b = (const float*)d_in[7];
    const float* rpn_cls_w = (const float*)d_in[8];
    const float* rpn_cls_b = (const float*)d_in[9];
    const float* fc_w      = (const float*)d_in[10];
    const float* fc_b      = (const float*)d_in[11];
    const float* reg_w     = (const float*)d_in[12];
    const float* reg_b     = (const float*)d_in[13];
    const float* cls_w     = (const float*)d_in[14];
    const float* cls_b     = (const float*)d_in[15];
    float* out = (float*)d_out;
    float* ws  = (float*)d_ws;

    float* fm   = ws + W_FM;
    float* zbuf = ws + W_ZERO;
    float* prop = ws + W_PROP;
    float* scr  = ws + W_SCR;
    float* flat = ws + W_FLAT;
    float* hf   = ws + W_HF;
    u16* a1i = (u16*)(ws + W_A1I);
    u16* b1i = (u16*)(ws + W_B1I);
    u16* fmi = (u16*)(ws + W_FMI);
    u16* b2i = (u16*)(ws + W_B2I);
    // rpn split-K(6) partials: z=0..3 alias flat/hf/... span (dead during rpn phase,
    // consumed by k_rpn_heads2 before k_roi/k_fc overwrite); z=4..5 in the part slot.
    float* partA = ws + W_FLAT;   // 4 * 2048*512 fp32
    float* partB = ws + W_PART;   // 2 * 2048*512 fp32 == 2048*1024 (conv1 partial z=1)

    k_prep_a1<<<1536, 256, 0, stream>>>(img, a1i, zbuf);
    k_prep_b1<<<768, 256, 0, stream>>>(cnn_w, b1i);
    k_prep_w2<<<512, 256, 0, stream>>>(rpn_w, b2i);
    // conv1: split-K(2) raw partials (fm, partB) -> fused reduce (bias+relu+split)
    k_gemm<0><<<dim3(16, 16, 2), 256, 0, stream>>>(a1i, b1i, fm, partB,
                                                   24 * 64, 24 * 64, 12, 1024, zbuf);
    k_c1_reduce<<<2048, 256, 0, stream>>>(partB, cnn_b, fm, fmi);
    // rpn: split-K 6 over 288 chunks -> 768 blocks = 3 blocks/CU
    k_gemm<1><<<dim3(16, 8, 6), 256, 0, stream>>>(fmi, b2i, partA, partB,
                                                  0, 288 * 64, 48, 512, zbuf);
    k_rpn_heads2<<<256, 256, 0, stream>>>(partA, partB, rpn_b, rpn_reg_w, rpn_reg_b,
                                          rpn_cls_w, rpn_cls_b, out, prop, scr);
    k_nms3<<<2, 512, 0, stream>>>(prop, scr, out);
    k_roi<<<dim3(4, 20, 2), 256, 0, stream>>>(fm, img_id, out + O_NMS_REG, flat, fc_b, hf);
    k_fc_mfma<<<dim3(4, 98), 256, 0, stream>>>(flat, fc_w, hf);
    k_heads<<<40, 64, 0, stream>>>(hf, reg_w, reg_b, cls_w, cls_b, out);
}